// Round 4
// baseline (431.896 us; speedup 1.0000x reference)
//
#include <hip/hip_runtime.h>
#include <stdint.h>

// MultiHeadAttention fwd. Round 4:
//  - inputs+weights converted to bf16 once; QKV proj uses global_load_lds path
//  - fused attn: K/V staged in XOR-swizzled LDS (shared by 4 waves), two-pass
//    no-max softmax, vectorized nontemporal attn stores from the P-bounce
// d_out = [out: 4194304 f32][attn: 134217728 f32]
// d_ws (main, 64MB): [xb 3x4M][Wb 4x1M][qkv 3x4M][ctx 4M] bf16
// q pre-scaled by 0.125 at projection (exact pow2).

#define DEV __device__ __forceinline__

typedef __attribute__((ext_vector_type(8))) short short8;
typedef __attribute__((ext_vector_type(4))) short short4v;
typedef __attribute__((ext_vector_type(4))) float f32x4;
typedef __attribute__((ext_vector_type(4))) uint32_t u32x4;

DEV short f2bf(float f) {  // round-to-nearest-even f32 -> bf16 bits
  uint32_t u = __builtin_bit_cast(uint32_t, f);
  u += 0x7fffu + ((u >> 16) & 1u);
  return (short)(u >> 16);
}

DEV uint32_t cvtpk_bf16(float a, float b) {  // hi.bf16(b) | lo.bf16(a), RNE
  uint32_t r;
  asm("v_cvt_pk_bf16_f32 %0, %1, %2" : "=v"(r) : "v"(a), "v"(b));
  return r;
}

DEV void gload_lds16(const void* g, void* l) {
  __builtin_amdgcn_global_load_lds(
      (const __attribute__((address_space(1))) void*)g,
      (__attribute__((address_space(3))) void*)l,
      16, 0, 0);
}

// Stage rows x (SPR*16B) bf16 tile into LDS: linear dest, source pre-swizzled
// so reads with byte^((row&7)<<4) see row-major data.
template<int UNITS, int SPR>
DEV void stage_swz(const short* src, int stride, char* lds, int tid) {
#pragma unroll
  for (int i = 0; i < UNITS; ++i) {
    const int u = tid + i * 256;
    const int r = u / SPR;
    const int s = (u % SPR) ^ (r & 7);
    gload_lds16(src + (size_t)r * stride + s * 8, lds + u * 16);
  }
}

DEV short8 ldsfrag(const char* lds, int row, int kbyte, int rowb) {
  return *(const short8*)(lds + row * rowb + (kbyte ^ ((row & 7) << 4)));
}

// ---------------------------------------------------------------------------
// Fused attention. Per block (z = b*16+h, qb = 128-row q block):
//  pass1: l[row] = sum_k exp(s) over 16 K-tiles (K staged in LDS, no max)
//  pass2: recompute s, P=exp(s)*inv_l -> attn (float4 nontemporal, assembled
//         from the PV bounce), PV MFMA with V staged in LDS.
// ---------------------------------------------------------------------------
__global__ __launch_bounds__(256) void attn_fused(
    const short* __restrict__ q, const short* __restrict__ k,
    const short* __restrict__ vT, float* __restrict__ attn,
    short* __restrict__ ctx) {
  __shared__ __align__(16) char Ks[128 * 128];     // 16KB
  __shared__ __align__(16) char Vs[64 * 256];      // 16KB
  __shared__ __align__(16) char Ps[4 * 32 * 128];  // 16KB (wave-private 4KB)

  const int tid = threadIdx.x;
  const int lane = tid & 63;
  const int wm = tid >> 6;  // wave owns q-rows [wm*32, wm*32+32)
  const int c = lane & 15;
  const int g = lane >> 4;
  // XCD chunk swizzle: 64 consecutive sids (4 heads) per XCD
  const int orig = blockIdx.x;
  const int sid = (orig & 7) * 64 + (orig >> 3);
  const int qb = sid & 15;
  const int z = sid >> 4;  // b*16+h

  const short* qz = q + (size_t)z * 131072 + (size_t)(qb * 128 + wm * 32) * 64;
  const short* kz = k + (size_t)z * 131072;
  const short* vz = vT + (size_t)z * 131072;
  float* az = attn + (size_t)z * 4194304 + (size_t)(qb * 128 + wm * 32) * 2048;

  // Q fragments (rows m*16+c, k-chunk kk*32+g*8) straight from global
  short8 qf[2][2];
#pragma unroll
  for (int m = 0; m < 2; ++m)
#pragma unroll
    for (int kk = 0; kk < 2; ++kk)
      qf[m][kk] = *(const short8*)(qz + (m * 16 + c) * 64 + kk * 32 + g * 8);

  // ---------------- pass 1: row sums of exp(s) ----------------
  float l_part[2][4];
#pragma unroll
  for (int m = 0; m < 2; ++m)
#pragma unroll
    for (int j = 0; j < 4; ++j) l_part[m][j] = 0.f;

  for (int kt = 0; kt < 16; ++kt) {
    if (kt) __syncthreads();
    stage_swz<4, 8>(kz + kt * 8192, 64, Ks, tid);
    __syncthreads();
    f32x4 s[2][8];
#pragma unroll
    for (int m = 0; m < 2; ++m)
#pragma unroll
      for (int n = 0; n < 8; ++n) s[m][n] = f32x4{0.f, 0.f, 0.f, 0.f};
#pragma unroll
    for (int kk = 0; kk < 2; ++kk) {
#pragma unroll
      for (int n = 0; n < 8; ++n) {
        const short8 bf = ldsfrag(Ks, n * 16 + c, kk * 64 + g * 16, 128);
        s[0][n] = __builtin_amdgcn_mfma_f32_16x16x32_bf16(qf[0][kk], bf,
                                                          s[0][n], 0, 0, 0);
        s[1][n] = __builtin_amdgcn_mfma_f32_16x16x32_bf16(qf[1][kk], bf,
                                                          s[1][n], 0, 0, 0);
      }
    }
#pragma unroll
    for (int m = 0; m < 2; ++m)
#pragma unroll
      for (int j = 0; j < 4; ++j)
#pragma unroll
        for (int n = 0; n < 8; ++n) l_part[m][j] += __expf(s[m][n][j]);
  }

  float inv_l[2][4];
#pragma unroll
  for (int m = 0; m < 2; ++m)
#pragma unroll
    for (int j = 0; j < 4; ++j) {
      float l = l_part[m][j];
      l += __shfl_xor(l, 1, 64);
      l += __shfl_xor(l, 2, 64);
      l += __shfl_xor(l, 4, 64);
      l += __shfl_xor(l, 8, 64);
      inv_l[m][j] = 1.0f / l;
    }

  // ---------------- pass 2: attn write + PV ----------------
  f32x4 o[2][4];
#pragma unroll
  for (int m = 0; m < 2; ++m)
#pragma unroll
    for (int n = 0; n < 4; ++n) o[m][n] = f32x4{0.f, 0.f, 0.f, 0.f};

  char* Pw = Ps + wm * 4096;  // wave-private 32 rows x 128B

  for (int kt = 0; kt < 16; ++kt) {
    __syncthreads();
    stage_swz<4, 8>(kz + kt * 8192, 64, Ks, tid);
    stage_swz<4, 16>(vz + kt * 128, 2048, Vs, tid);
    __syncthreads();
    f32x4 s[2][8];
#pragma unroll
    for (int m = 0; m < 2; ++m)
#pragma unroll
      for (int n = 0; n < 8; ++n) s[m][n] = f32x4{0.f, 0.f, 0.f, 0.f};
#pragma unroll
    for (int kk = 0; kk < 2; ++kk) {
#pragma unroll
      for (int n = 0; n < 8; ++n) {
        const short8 bf = ldsfrag(Ks, n * 16 + c, kk * 64 + g * 16, 128);
        s[0][n] = __builtin_amdgcn_mfma_f32_16x16x32_bf16(qf[0][kk], bf,
                                                          s[0][n], 0, 0, 0);
        s[1][n] = __builtin_amdgcn_mfma_f32_16x16x32_bf16(qf[1][kk], bf,
                                                          s[1][n], 0, 0, 0);
      }
    }
    // P = exp(s) * inv_l
#pragma unroll
    for (int m = 0; m < 2; ++m)
#pragma unroll
      for (int j = 0; j < 4; ++j) {
        const float il = inv_l[m][j];
#pragma unroll
        for (int n = 0; n < 8; ++n) s[m][n][j] = __expf(s[m][n][j]) * il;
      }
    // PV chunks of k'=32 via wave-private LDS bounce; attn stores come from
    // the bounce read (lanes hold 8 consecutive floats of one row there).
#pragma unroll
    for (int kc = 0; kc < 4; ++kc) {
#pragma unroll
      for (int m = 0; m < 2; ++m)
#pragma unroll
        for (int nn = 0; nn < 2; ++nn)
#pragma unroll
          for (int j = 0; j < 4; ++j) {
            const int r = m * 16 + g * 4 + j;
            *(float*)(Pw + r * 128 +
                      (((nn * 16 + c) * 4) ^ ((r & 7) << 4))) =
                s[m][kc * 2 + nn][j];
          }
      short8 paf[2];
#pragma unroll
      for (int m = 0; m < 2; ++m) {
        const int r = m * 16 + c;
        const int X = (r & 7) << 4;
        const f32x4 lo = *(const f32x4*)(Pw + r * 128 + ((g * 32) ^ X));
        const f32x4 hi = *(const f32x4*)(Pw + r * 128 + ((g * 32 + 16) ^ X));
        float* dst = az + (size_t)r * 2048 + kt * 128 + kc * 32 + g * 8;
        __builtin_nontemporal_store(lo, (f32x4*)dst);
        __builtin_nontemporal_store(hi, (f32x4*)(dst + 4));
        u32x4 pk;
        pk[0] = cvtpk_bf16(lo[0], lo[1]);
        pk[1] = cvtpk_bf16(lo[2], lo[3]);
        pk[2] = cvtpk_bf16(hi[0], hi[1]);
        pk[3] = cvtpk_bf16(hi[2], hi[3]);
        paf[m] = __builtin_bit_cast(short8, pk);
      }
#pragma unroll
      for (int n2 = 0; n2 < 4; ++n2) {
        const short8 vf = ldsfrag(Vs, n2 * 16 + c, kc * 64 + g * 16, 256);
        o[0][n2] = __builtin_amdgcn_mfma_f32_16x16x32_bf16(paf[0], vf,
                                                           o[0][n2], 0, 0, 0);
        o[1][n2] = __builtin_amdgcn_mfma_f32_16x16x32_bf16(paf[1], vf,
                                                           o[1][n2], 0, 0, 0);
      }
    }
  }

  // epilogue: ctx[b, s, h*64+d] bf16 (re-read by out-proj: keep in L2)
  const int b = z >> 4, h = z & 15;
#pragma unroll
  for (int m = 0; m < 2; ++m)
#pragma unroll
    for (int n2 = 0; n2 < 4; ++n2)
#pragma unroll
      for (int j = 0; j < 4; ++j)
        ctx[((size_t)(b * 2048 + qb * 128 + wm * 32 + m * 16 + g * 4 + j)) *
                1024 + h * 64 + n2 * 16 + c] = f2bf(o[m][n2][j]);
}

// ---------------------------------------------------------------------------
// NT bf16 GEMM. C[m,n] = sum_k A[m,k]*B[n,k]. XCD chunk-swizzled 1D grid.
// ---------------------------------------------------------------------------
enum { M_PROJ = 0, M_OUT = 3 };

struct GP {
  const void* A0; const void* A1; const void* A2;
  const short* B;
  const float* b0; const float* b1; const float* b2;
  void* C;
  int lda, ldb, K;
  long aBS, bBS;
};

template<int WM, int WN, int AM, int AN, bool CONVA, int MODE>
__global__ __launch_bounds__(256) void gemm_nt(GP p) {
  constexpr int BM = WM * 16 * AM;
  constexpr int BN = WN * 16 * AN;
  static_assert(WM * WN == 4, "4 waves / 256 threads");
  __shared__ __align__(16) char As[BM * 128];
  __shared__ __align__(16) char Bs[BN * 128];

  const int tid = threadIdx.x;
  const int lane = tid & 63;
  const int z = blockIdx.y;
  // bijective XCD chunk swizzle over 256 blocks (M/BM=32 x N/BN=8)
  const int orig = blockIdx.x;
  const int sid = (orig & 7) * 32 + (orig >> 3);
  const int bm0 = (sid >> 3) * BM;
  const int bn0 = (sid & 7) * BN;

  const void* Aroot; const float* bias;
  if constexpr (MODE == M_PROJ) {
    if constexpr (CONVA)
      Aroot = (z == 0) ? p.A0 : (z == 1 ? p.A1 : p.A2);
    else
      Aroot = p.A0;  // + z*aBS in the load
    bias = (z == 0) ? p.b0 : (z == 1 ? p.b1 : p.b2);
  } else {
    Aroot = p.A0; bias = p.b0;
  }

  f32x4 acc[AM][AN];
#pragma unroll
  for (int m = 0; m < AM; ++m)
#pragma unroll
    for (int n = 0; n < AN; ++n) acc[m][n] = f32x4{0.f, 0.f, 0.f, 0.f};

  const int wave = tid >> 6;
  const int wm = wave / WN;
  const int wn = wave % WN;

  const int nK = p.K >> 6;
  for (int kt = 0; kt < nK; ++kt) {
    if constexpr (CONVA) {  // fp32 source: reg-stage + convert + swizzled write
      const float* Af = (const float*)Aroot + (size_t)z * p.aBS +
                        (size_t)bm0 * p.lda + kt * 64;
#pragma unroll
      for (int sw = 0; sw < BM / 16; ++sw) {
        const int r = sw * 16 + (tid >> 4);
        const int s8 = tid & 15;
        const float4 v = *(const float4*)(Af + (size_t)r * p.lda + s8 * 4);
        short4v oo;
        oo[0] = f2bf(v.x); oo[1] = f2bf(v.y); oo[2] = f2bf(v.z); oo[3] = f2bf(v.w);
        const int boff = (r * 128 + s8 * 8) ^ ((r & 7) << 4);
        *(short4v*)(As + boff) = oo;
      }
    } else {  // bf16 source: global_load_lds, linear dest + pre-swizzled src
      const short* Ab = (const short*)Aroot + (size_t)z * p.aBS +
                        (size_t)bm0 * p.lda + kt * 64;
#pragma unroll
      for (int sw = 0; sw < BM / 32; ++sw) {
        const int r = sw * 32 + (tid >> 3);
        const int c8 = (tid & 7) ^ (r & 7);
        gload_lds16(Ab + (size_t)r * p.lda + c8 * 8, As + (sw * 256 + tid) * 16);
      }
    }
    {
      const short* Bb = p.B + (size_t)z * p.bBS + (size_t)bn0 * p.ldb + kt * 64;
#pragma unroll
      for (int sw = 0; sw < BN / 32; ++sw) {
        const int r = sw * 32 + (tid >> 3);
        const int c8 = (tid & 7) ^ (r & 7);
        gload_lds16(Bb + (size_t)r * p.ldb + c8 * 8, Bs + (sw * 256 + tid) * 16);
      }
    }
    __syncthreads();
#pragma unroll
    for (int kk = 0; kk < 2; ++kk) {
      const int kb = kk * 64 + (lane >> 4) * 16;
      short8 aF[AM], bF[AN];
#pragma unroll
      for (int m = 0; m < AM; ++m) {
        const int r = wm * (16 * AM) + m * 16 + (lane & 15);
        aF[m] = *(const short8*)(As + ((r * 128 + kb) ^ ((r & 7) << 4)));
      }
#pragma unroll
      for (int n = 0; n < AN; ++n) {
        const int r = wn * (16 * AN) + n * 16 + (lane & 15);
        bF[n] = *(const short8*)(Bs + ((r * 128 + kb) ^ ((r & 7) << 4)));
      }
#pragma unroll
      for (int m = 0; m < AM; ++m)
#pragma unroll
        for (int n = 0; n < AN; ++n)
          acc[m][n] = __builtin_amdgcn_mfma_f32_16x16x32_bf16(
              aF[m], bF[n], acc[m][n], 0, 0, 0);
    }
    __syncthreads();
  }

#pragma unroll
  for (int m = 0; m < AM; ++m) {
#pragma unroll
    for (int n = 0; n < AN; ++n) {
#pragma unroll
      for (int j = 0; j < 4; ++j) {
        const int gm = bm0 + wm * (16 * AM) + m * 16 + ((lane >> 4) << 2) + j;
        const int gn = bn0 + wn * (16 * AN) + n * 16 + (lane & 15);
        const float v = acc[m][n][j];
        if constexpr (MODE == M_PROJ) {
          float vb = v + bias[gn];
          if (z == 0) vb *= 0.125f;  // fold 1/sqrt(depth) into q (exact pow2)
          const int b = gm >> 11, s = gm & 2047;
          const int h = gn >> 6, d = gn & 63;
          short* C = (short*)p.C;
          if (z < 2) {  // q,k: [b,h,s,d]
            C[(size_t)z * 4194304 + (((size_t)(b * 16 + h) * 2048 + s) * 64 + d)] = f2bf(vb);
          } else {      // v transposed: [b,h,d,s]
            C[(size_t)2 * 4194304 + (((size_t)(b * 16 + h) * 64 + d) * 2048 + s)] = f2bf(vb);
          }
        } else {  // M_OUT: never re-read -> nontemporal
          __builtin_nontemporal_store(
              v + bias[gn], (float*)p.C + (size_t)gm * 1024 + gn);
        }
      }
    }
  }
}

// Convert inputs (y<3: 4M elems each) and weights (y>=3: 1M each) to bf16.
__global__ __launch_bounds__(256) void cvt_all(
    const float* q, const float* k, const float* v, const float* w0,
    const float* w1, const float* w2, const float* w3, short* xb, short* Wb) {
  const int y = blockIdx.y;
  const float* src; short* dst; int n;
  if (y < 3) {
    src = (y == 0) ? q : (y == 1) ? k : v;
    dst = xb + (size_t)y * 4194304; n = 4194304;
  } else {
    src = (y == 3) ? w0 : (y == 4) ? w1 : (y == 5) ? w2 : w3;
    dst = Wb + (size_t)(y - 3) * 1048576; n = 1048576;
  }
  const int i = (blockIdx.x * 256 + threadIdx.x) * 4;
  if (i >= n) return;
  const float4 val = *(const float4*)(src + i);
  short4v s;
  s[0] = f2bf(val.x); s[1] = f2bf(val.y); s[2] = f2bf(val.z); s[3] = f2bf(val.w);
  *(short4v*)(dst + i) = s;
}

// Weights-only conversion (fallback path, ws too small for xb).
__global__ __launch_bounds__(256) void cvt_w(const float* w0, const float* w1,
                                             const float* w2, const float* w3,
                                             short* out) {
  const float* w = (blockIdx.y == 0) ? w0 : (blockIdx.y == 1) ? w1
                 : (blockIdx.y == 2) ? w2 : w3;
  short* o = out + (size_t)blockIdx.y * 1048576;
  const int i = (blockIdx.x * 256 + threadIdx.x) * 4;
  const float4 v = *(const float4*)(w + i);
  short4v s;
  s[0] = f2bf(v.x); s[1] = f2bf(v.y); s[2] = f2bf(v.z); s[3] = f2bf(v.w);
  *(short4v*)(o + i) = s;
}

extern "C" void kernel_launch(void* const* d_in, const int* in_sizes, int n_in,
                              void* d_out, int out_size, void* d_ws, size_t ws_size,
                              hipStream_t stream) {
  const float* query = (const float*)d_in[0];
  const float* key_  = (const float*)d_in[1];
  const float* value = (const float*)d_in[2];
  const float* Wq = (const float*)d_in[3];
  const float* bq = (const float*)d_in[4];
  const float* Wk = (const float*)d_in[5];
  const float* bk = (const float*)d_in[6];
  const float* Wv = (const float*)d_in[7];
  const float* bv = (const float*)d_in[8];
  const float* Wo = (const float*)d_in[9];
  const float* bo = (const float*)d_in[10];

  float* out  = (float*)d_out;
  float* attn = (float*)d_out + 4194304;
  short* ws   = (short*)d_ws;

  const bool big_ws = ws_size >= (size_t)64 * 1024 * 1024;

  if (big_ws) {
    short* xb  = ws;                       // 3 x 4194304
    short* Wb  = ws + 3 * 4194304;         // 4 x 1048576
    short* qkv = ws + 3 * 4194304 + 4 * 1048576;  // 3 x 4194304
    short* ctx = qkv + 3 * 4194304;        // 4194304

    cvt_all<<<dim3(4096, 7), 256, 0, stream>>>(query, key_, value, Wq, Wk, Wv,
                                               Wo, xb, Wb);
    {  // QKV projections from bf16 inputs (fast path)
      GP p{};
      p.A0 = xb;
      p.B = Wb; p.b0 = bq; p.b1 = bk; p.b2 = bv;
      p.C = qkv;
      p.lda = 1024; p.ldb = 1024; p.K = 1024;
      p.aBS = 4194304; p.bBS = 1048576;
      gemm_nt<2, 2, 4, 4, false, M_PROJ><<<dim3(256, 3), 256, 0, stream>>>(p);
    }
    attn_fused<<<dim3(512), 256, 0, stream>>>(
        qkv, qkv + 4194304, qkv + 2 * 4194304, attn, ctx);
    {  // out = ctx @ Wo^T + bo
      GP p{};
      p.A0 = ctx;
      p.B = Wb + 3 * 1048576;
      p.b0 = bo;
      p.C = out;
      p.lda = 1024; p.ldb = 1024; p.K = 1024;
      p.aBS = 0; p.bBS = 0;
      gemm_nt<2, 2, 4, 4, false, M_OUT><<<dim3(256, 1), 256, 0, stream>>>(p);
    }
  } else {  // fallback: R3 layout, CONVA projections (40MB)
    short* Wb  = ws;                       // 4 x 1048576
    short* qkv = ws + 4194304;             // 3 x 4194304
    short* ctx = ws + 4 * 4194304;         // 4194304

    cvt_w<<<dim3(1024, 4), 256, 0, stream>>>(Wq, Wk, Wv, Wo, Wb);
    {
      GP p{};
      p.A0 = query; p.A1 = key_; p.A2 = value;
      p.B = Wb; p.b0 = bq; p.b1 = bk; p.b2 = bv;
      p.C = qkv;
      p.lda = 1024; p.ldb = 1024; p.K = 1024;
      p.aBS = 0; p.bBS = 1048576;
      gemm_nt<2, 2, 4, 4, true, M_PROJ><<<dim3(256, 3), 256, 0, stream>>>(p);
    }
    attn_fused<<<dim3(512), 256, 0, stream>>>(
        qkv, qkv + 4194304, qkv + 2 * 4194304, attn, ctx);
    {
      GP p{};
      p.A0 = ctx;
      p.B = Wb + 3 * 1048576;
      p.b0 = bo;
      p.C = out;
      p.lda = 1024; p.ldb = 1024; p.K = 1024;
      p.aBS = 0; p.bBS = 0;
      gemm_nt<2, 2, 4, 4, false, M_OUT><<<dim3(256, 1), 256, 0, stream>>>(p);
    }
  }
}

// Round 5
// 302.869 us; speedup vs baseline: 1.4260x; 1.4260x over previous
//
#include <hip/hip_runtime.h>
#include <stdint.h>

// MultiHeadAttention fwd. Round 5:
//  - attn: barrier-free two-pass (R3 structure): K/V fragment loads direct
//    from global (L2-resident, FETCH=12MB proved it), LDS only for the
//    wave-private P bounce, SCALAR nontemporal attn stores (64B-contiguous
//    per 16-lane group; R4's f32x4 pattern caused 1.73x write amplification).
//  - QKV proj from pre-converted bf16 inputs (global_load_lds path).
// d_out = [out: 4194304 f32][attn: 134217728 f32]
// d_ws (main, 64MB): [xb 3x4M][Wb 4x1M][qkv 3x4M][ctx 4M] bf16
// q pre-scaled by 0.125 at projection (exact pow2).

#define DEV __device__ __forceinline__

typedef __attribute__((ext_vector_type(8))) short short8;
typedef __attribute__((ext_vector_type(4))) short short4v;
typedef __attribute__((ext_vector_type(4))) float f32x4;
typedef __attribute__((ext_vector_type(4))) uint32_t u32x4;

DEV short f2bf(float f) {  // round-to-nearest-even f32 -> bf16 bits
  uint32_t u = __builtin_bit_cast(uint32_t, f);
  u += 0x7fffu + ((u >> 16) & 1u);
  return (short)(u >> 16);
}

DEV uint32_t cvtpk_bf16(float a, float b) {  // hi.bf16(b) | lo.bf16(a), RNE
  uint32_t r;
  asm("v_cvt_pk_bf16_f32 %0, %1, %2" : "=v"(r) : "v"(a), "v"(b));
  return r;
}

DEV void gload_lds16(const void* g, void* l) {
  __builtin_amdgcn_global_load_lds(
      (const __attribute__((address_space(1))) void*)g,
      (__attribute__((address_space(3))) void*)l,
      16, 0, 0);
}

// ---------------------------------------------------------------------------
// Fused attention, barrier-free. Per block (z = b*16+h, qb = 128-row block):
//  Q frags in regs; K,V fragments loaded directly from global (L2-resident).
//  pass1: l[row] = sum_k exp(s)   (no max; deferred cross-lane reduce)
//  pass2: recompute s, P = exp(s)*inv_l -> attn (scalar nontemporal, 64B
//         coalesced), PV via wave-private LDS bounce. No __syncthreads.
// ---------------------------------------------------------------------------
__global__ __launch_bounds__(256) void attn_fused(
    const short* __restrict__ q, const short* __restrict__ k,
    const short* __restrict__ vT, float* __restrict__ attn,
    short* __restrict__ ctx) {
  __shared__ __align__(16) char Ps[4 * 32 * 128];  // per-wave 32x32 f32

  const int tid = threadIdx.x;
  const int lane = tid & 63;
  const int wm = tid >> 6;      // wave owns q-rows [wm*32, wm*32+32)
  const int c = lane & 15;
  const int g = lane >> 4;
  // XCD chunk swizzle (512 blocks, 64 per XCD -> 4 heads per XCD L2)
  const int orig = blockIdx.x;
  const int sid = (orig & 7) * 64 + (orig >> 3);
  const int qb = sid & 15;
  const int z = sid >> 4;       // b*16+h

  const short* qz = q + (size_t)z * 131072 + (size_t)(qb * 128 + wm * 32) * 64;
  const short* kz = k + (size_t)z * 131072;
  const short* vz = vT + (size_t)z * 131072;
  float* az = attn + (size_t)z * 4194304 + (size_t)(qb * 128 + wm * 32) * 2048;

  // Q fragments (rows m*16+c, k-chunk kk*32+g*8)
  short8 qf[2][2];
#pragma unroll
  for (int m = 0; m < 2; ++m)
#pragma unroll
    for (int kk = 0; kk < 2; ++kk)
      qf[m][kk] = *(const short8*)(qz + (m * 16 + c) * 64 + kk * 32 + g * 8);

  // ---------------- pass 1: row sums of exp(s) ----------------
  float l_part[2][4];
#pragma unroll
  for (int m = 0; m < 2; ++m)
#pragma unroll
    for (int j = 0; j < 4; ++j) l_part[m][j] = 0.f;

  for (int kt = 0; kt < 16; ++kt) {
    const short* kzt = kz + kt * 8192;
    f32x4 s[2][8];
#pragma unroll
    for (int m = 0; m < 2; ++m)
#pragma unroll
      for (int n = 0; n < 8; ++n) s[m][n] = f32x4{0.f, 0.f, 0.f, 0.f};
#pragma unroll
    for (int kk = 0; kk < 2; ++kk) {
#pragma unroll
      for (int n = 0; n < 8; ++n) {
        const short8 bf =
            *(const short8*)(kzt + (n * 16 + c) * 64 + kk * 32 + g * 8);
        s[0][n] = __builtin_amdgcn_mfma_f32_16x16x32_bf16(qf[0][kk], bf,
                                                          s[0][n], 0, 0, 0);
        s[1][n] = __builtin_amdgcn_mfma_f32_16x16x32_bf16(qf[1][kk], bf,
                                                          s[1][n], 0, 0, 0);
      }
    }
#pragma unroll
    for (int m = 0; m < 2; ++m)
#pragma unroll
      for (int j = 0; j < 4; ++j)
#pragma unroll
        for (int n = 0; n < 8; ++n) l_part[m][j] += __expf(s[m][n][j]);
  }

  float inv_l[2][4];
#pragma unroll
  for (int m = 0; m < 2; ++m)
#pragma unroll
    for (int j = 0; j < 4; ++j) {
      float l = l_part[m][j];
      l += __shfl_xor(l, 1, 64);
      l += __shfl_xor(l, 2, 64);
      l += __shfl_xor(l, 4, 64);
      l += __shfl_xor(l, 8, 64);
      inv_l[m][j] = 1.0f / l;
    }

  // ---------------- pass 2: attn write + PV ----------------
  f32x4 o[2][4];
#pragma unroll
  for (int m = 0; m < 2; ++m)
#pragma unroll
    for (int n = 0; n < 4; ++n) o[m][n] = f32x4{0.f, 0.f, 0.f, 0.f};

  char* Pw = Ps + wm * 4096;  // wave-private 32 rows x 128B

  for (int kt = 0; kt < 16; ++kt) {
    const short* kzt = kz + kt * 8192;
    f32x4 s[2][8];
#pragma unroll
    for (int m = 0; m < 2; ++m)
#pragma unroll
      for (int n = 0; n < 8; ++n) s[m][n] = f32x4{0.f, 0.f, 0.f, 0.f};
#pragma unroll
    for (int kk = 0; kk < 2; ++kk) {
#pragma unroll
      for (int n = 0; n < 8; ++n) {
        const short8 bf =
            *(const short8*)(kzt + (n * 16 + c) * 64 + kk * 32 + g * 8);
        s[0][n] = __builtin_amdgcn_mfma_f32_16x16x32_bf16(qf[0][kk], bf,
                                                          s[0][n], 0, 0, 0);
        s[1][n] = __builtin_amdgcn_mfma_f32_16x16x32_bf16(qf[1][kk], bf,
                                                          s[1][n], 0, 0, 0);
      }
    }
    // P = exp(s) * inv_l; scalar NT stores (64B contiguous per 16-lane group)
#pragma unroll
    for (int m = 0; m < 2; ++m)
#pragma unroll
      for (int j = 0; j < 4; ++j) {
        const float il = inv_l[m][j];
#pragma unroll
        for (int n = 0; n < 8; ++n) s[m][n][j] = __expf(s[m][n][j]) * il;
      }
#pragma unroll
    for (int m = 0; m < 2; ++m)
#pragma unroll
      for (int n = 0; n < 8; ++n)
#pragma unroll
        for (int j = 0; j < 4; ++j)
          __builtin_nontemporal_store(
              s[m][n][j], az + (size_t)(m * 16 + g * 4 + j) * 2048 +
                              kt * 128 + n * 16 + c);
    // PV: 4 chunks of k'=32 through wave-private LDS transpose bounce
#pragma unroll
    for (int kc = 0; kc < 4; ++kc) {
#pragma unroll
      for (int m = 0; m < 2; ++m)
#pragma unroll
        for (int nn = 0; nn < 2; ++nn)
#pragma unroll
          for (int j = 0; j < 4; ++j) {
            const int r = m * 16 + g * 4 + j;
            *(float*)(Pw + r * 128 +
                      (((nn * 16 + c) * 4) ^ ((r & 7) << 4))) =
                s[m][kc * 2 + nn][j];
          }
      short8 paf[2];
#pragma unroll
      for (int m = 0; m < 2; ++m) {
        const int r = m * 16 + c;
        const int X = (r & 7) << 4;
        const f32x4 lo = *(const f32x4*)(Pw + r * 128 + ((g * 32) ^ X));
        const f32x4 hi = *(const f32x4*)(Pw + r * 128 + ((g * 32 + 16) ^ X));
        u32x4 pk;
        pk[0] = cvtpk_bf16(lo[0], lo[1]);
        pk[1] = cvtpk_bf16(lo[2], lo[3]);
        pk[2] = cvtpk_bf16(hi[0], hi[1]);
        pk[3] = cvtpk_bf16(hi[2], hi[3]);
        paf[m] = __builtin_bit_cast(short8, pk);
      }
#pragma unroll
      for (int n2 = 0; n2 < 4; ++n2) {
        const short8 vf = *(const short8*)(vz + (size_t)(n2 * 16 + c) * 2048 +
                                           kt * 128 + kc * 32 + g * 8);
        o[0][n2] = __builtin_amdgcn_mfma_f32_16x16x32_bf16(paf[0], vf,
                                                           o[0][n2], 0, 0, 0);
        o[1][n2] = __builtin_amdgcn_mfma_f32_16x16x32_bf16(paf[1], vf,
                                                           o[1][n2], 0, 0, 0);
      }
    }
  }

  // epilogue: ctx[b, s, h*64+d] bf16 (re-read by out-proj: keep in L2)
  const int b = z >> 4, h = z & 15;
#pragma unroll
  for (int m = 0; m < 2; ++m)
#pragma unroll
    for (int n2 = 0; n2 < 4; ++n2)
#pragma unroll
      for (int j = 0; j < 4; ++j)
        ctx[((size_t)(b * 2048 + qb * 128 + wm * 32 + m * 16 + g * 4 + j)) *
                1024 + h * 64 + n2 * 16 + c] = f2bf(o[m][n2][j]);
}

// ---------------------------------------------------------------------------
// NT bf16 GEMM. C[m,n] = sum_k A[m,k]*B[n,k]. XCD chunk-swizzled 1D grid.
// ---------------------------------------------------------------------------
enum { M_PROJ = 0, M_OUT = 3 };

struct GP {
  const void* A0; const void* A1; const void* A2;
  const short* B;
  const float* b0; const float* b1; const float* b2;
  void* C;
  int lda, ldb, K;
  long aBS, bBS;
};

template<int WM, int WN, int AM, int AN, bool CONVA, int MODE>
__global__ __launch_bounds__(256) void gemm_nt(GP p) {
  constexpr int BM = WM * 16 * AM;
  constexpr int BN = WN * 16 * AN;
  static_assert(WM * WN == 4, "4 waves / 256 threads");
  __shared__ __align__(16) char As[BM * 128];
  __shared__ __align__(16) char Bs[BN * 128];

  const int tid = threadIdx.x;
  const int lane = tid & 63;
  const int z = blockIdx.y;
  // bijective XCD chunk swizzle over 256 blocks (M/BM=32 x N/BN=8)
  const int orig = blockIdx.x;
  const int sid = (orig & 7) * 32 + (orig >> 3);
  const int bm0 = (sid >> 3) * BM;
  const int bn0 = (sid & 7) * BN;

  const void* Aroot; const float* bias;
  if constexpr (MODE == M_PROJ) {
    if constexpr (CONVA)
      Aroot = (z == 0) ? p.A0 : (z == 1 ? p.A1 : p.A2);
    else
      Aroot = p.A0;  // + z*aBS in the load
    bias = (z == 0) ? p.b0 : (z == 1 ? p.b1 : p.b2);
  } else {
    Aroot = p.A0; bias = p.b0;
  }

  f32x4 acc[AM][AN];
#pragma unroll
  for (int m = 0; m < AM; ++m)
#pragma unroll
    for (int n = 0; n < AN; ++n) acc[m][n] = f32x4{0.f, 0.f, 0.f, 0.f};

  const int wave = tid >> 6;
  const int wm = wave / WN;
  const int wn = wave % WN;

  const int nK = p.K >> 6;
  for (int kt = 0; kt < nK; ++kt) {
    if constexpr (CONVA) {  // fp32 source: reg-stage + convert + swizzled write
      const float* Af = (const float*)Aroot + (size_t)z * p.aBS +
                        (size_t)bm0 * p.lda + kt * 64;
#pragma unroll
      for (int sw = 0; sw < BM / 16; ++sw) {
        const int r = sw * 16 + (tid >> 4);
        const int s8 = tid & 15;
        const float4 v = *(const float4*)(Af + (size_t)r * p.lda + s8 * 4);
        short4v oo;
        oo[0] = f2bf(v.x); oo[1] = f2bf(v.y); oo[2] = f2bf(v.z); oo[3] = f2bf(v.w);
        const int boff = (r * 128 + s8 * 8) ^ ((r & 7) << 4);
        *(short4v*)(As + boff) = oo;
      }
    } else {  // bf16 source: global_load_lds, linear dest + pre-swizzled src
      const short* Ab = (const short*)Aroot + (size_t)z * p.aBS +
                        (size_t)bm0 * p.lda + kt * 64;
#pragma unroll
      for (int sw = 0; sw < BM / 32; ++sw) {
        const int r = sw * 32 + (tid >> 3);
        const int c8 = (tid & 7) ^ (r & 7);
        gload_lds16(Ab + (size_t)r * p.lda + c8 * 8, As + (sw * 256 + tid) * 16);
      }
    }
    {
      const short* Bb = p.B + (size_t)z * p.bBS + (size_t)bn0 * p.ldb + kt * 64;
#pragma unroll
      for (int sw = 0; sw < BN / 32; ++sw) {
        const int r = sw * 32 + (tid >> 3);
        const int c8 = (tid & 7) ^ (r & 7);
        gload_lds16(Bb + (size_t)r * p.ldb + c8 * 8, Bs + (sw * 256 + tid) * 16);
      }
    }
    __syncthreads();
#pragma unroll
    for (int kk = 0; kk < 2; ++kk) {
      const int kb = kk * 64 + (lane >> 4) * 16;
      short8 aF[AM], bF[AN];
#pragma unroll
      for (int m = 0; m < AM; ++m) {
        const int r = wm * (16 * AM) + m * 16 + (lane & 15);
        aF[m] = *(const short8*)(As + ((r * 128 + kb) ^ ((r & 7) << 4)));
      }
#pragma unroll
      for (int n = 0; n < AN; ++n) {
        const int r = wn * (16 * AN) + n * 16 + (lane & 15);
        bF[n] = *(const short8*)(Bs + ((r * 128 + kb) ^ ((r & 7) << 4)));
      }
#pragma unroll
      for (int m = 0; m < AM; ++m)
#pragma unroll
        for (int n = 0; n < AN; ++n)
          acc[m][n] = __builtin_amdgcn_mfma_f32_16x16x32_bf16(
              aF[m], bF[n], acc[m][n], 0, 0, 0);
    }
    __syncthreads();
  }

#pragma unroll
  for (int m = 0; m < AM; ++m) {
#pragma unroll
    for (int n = 0; n < AN; ++n) {
#pragma unroll
      for (int j = 0; j < 4; ++j) {
        const int gm = bm0 + wm * (16 * AM) + m * 16 + ((lane >> 4) << 2) + j;
        const int gn = bn0 + wn * (16 * AN) + n * 16 + (lane & 15);
        const float v = acc[m][n][j];
        if constexpr (MODE == M_PROJ) {
          float vb = v + bias[gn];
          if (z == 0) vb *= 0.125f;  // fold 1/sqrt(depth) into q (exact pow2)
          const int b = gm >> 11, s = gm & 2047;
          const int h = gn >> 6, d = gn & 63;
          short* C = (short*)p.C;
          if (z < 2) {  // q,k: [b,h,s,d]
            C[(size_t)z * 4194304 + (((size_t)(b * 16 + h) * 2048 + s) * 64 + d)] = f2bf(vb);
          } else {      // v transposed: [b,h,d,s]
            C[(size_t)2 * 4194304 + (((size_t)(b * 16 + h) * 64 + d) * 2048 + s)] = f2bf(vb);
          }
        } else {  // M_OUT: never re-read -> nontemporal
          __builtin_nontemporal_store(
              v + bias[gn], (float*)p.C + (size_t)gm * 1024 + gn);
        }
      }
    }
  }
}

// Convert inputs (y<3: 4M elems each) and weights (y>=3: 1M each) to bf16.
__global__ __launch_bounds__(256) void cvt_all(
    const float* q, const float* k, const float* v, const float* w0,
    const float* w1, const float* w2, const float* w3, short* xb, short* Wb) {
  const int y = blockIdx.y;
  const float* src; short* dst; int n;
  if (y < 3) {
    src = (y == 0) ? q : (y == 1) ? k : v;
    dst = xb + (size_t)y * 4194304; n = 4194304;
  } else {
    src = (y == 3) ? w0 : (y == 4) ? w1 : (y == 5) ? w2 : w3;
    dst = Wb + (size_t)(y - 3) * 1048576; n = 1048576;
  }
  const int i = (blockIdx.x * 256 + threadIdx.x) * 4;
  if (i >= n) return;
  const float4 val = *(const float4*)(src + i);
  short4v s;
  s[0] = f2bf(val.x); s[1] = f2bf(val.y); s[2] = f2bf(val.z); s[3] = f2bf(val.w);
  *(short4v*)(dst + i) = s;
}

// Weights-only conversion (fallback path, ws too small for xb).
__global__ __launch_bounds__(256) void cvt_w(const float* w0, const float* w1,
                                             const float* w2, const float* w3,
                                             short* out) {
  const float* w = (blockIdx.y == 0) ? w0 : (blockIdx.y == 1) ? w1
                 : (blockIdx.y == 2) ? w2 : w3;
  short* o = out + (size_t)blockIdx.y * 1048576;
  const int i = (blockIdx.x * 256 + threadIdx.x) * 4;
  const float4 v = *(const float4*)(w + i);
  short4v s;
  s[0] = f2bf(v.x); s[1] = f2bf(v.y); s[2] = f2bf(v.z); s[3] = f2bf(v.w);
  *(short4v*)(o + i) = s;
}

extern "C" void kernel_launch(void* const* d_in, const int* in_sizes, int n_in,
                              void* d_out, int out_size, void* d_ws, size_t ws_size,
                              hipStream_t stream) {
  const float* query = (const float*)d_in[0];
  const float* key_  = (const float*)d_in[1];
  const float* value = (const float*)d_in[2];
  const float* Wq = (const float*)d_in[3];
  const float* bq = (const float*)d_in[4];
  const float* Wk = (const float*)d_in[5];
  const float* bk = (const float*)d_in[6];
  const float* Wv = (const float*)d_in[7];
  const float* bv = (const float*)d_in[8];
  const float* Wo = (const float*)d_in[9];
  const float* bo = (const float*)d_in[10];

  float* out  = (float*)d_out;
  float* attn = (float*)d_out + 4194304;
  short* ws   = (short*)d_ws;

  const bool big_ws = ws_size >= (size_t)64 * 1024 * 1024;

  if (big_ws) {
    short* xb  = ws;                       // 3 x 4194304
    short* Wb  = ws + 3 * 4194304;         // 4 x 1048576
    short* qkv = ws + 3 * 4194304 + 4 * 1048576;  // 3 x 4194304
    short* ctx = qkv + 3 * 4194304;        // 4194304

    cvt_all<<<dim3(4096, 7), 256, 0, stream>>>(query, key_, value, Wq, Wk, Wv,
                                               Wo, xb, Wb);
    {  // QKV projections from bf16 inputs (fast path)
      GP p{};
      p.A0 = xb;
      p.B = Wb; p.b0 = bq; p.b1 = bk; p.b2 = bv;
      p.C = qkv;
      p.lda = 1024; p.ldb = 1024; p.K = 1024;
      p.aBS = 4194304; p.bBS = 1048576;
      gemm_nt<2, 2, 4, 4, false, M_PROJ><<<dim3(256, 3), 256, 0, stream>>>(p);
    }
    attn_fused<<<dim3(512), 256, 0, stream>>>(
        qkv, qkv + 4194304, qkv + 2 * 4194304, attn, ctx);
    {  // out = ctx @ Wo^T + bo
      GP p{};
      p.A0 = ctx;
      p.B = Wb + 3 * 1048576;
      p.b0 = bo;
      p.C = out;
      p.lda = 1024; p.ldb = 1024; p.K = 1024;
      p.aBS = 0; p.bBS = 0;
      gemm_nt<2, 2, 4, 4, false, M_OUT><<<dim3(256, 1), 256, 0, stream>>>(p);
    }
  } else {  // fallback: CONVA projections (40MB layout)
    short* Wb  = ws;                       // 4 x 1048576
    short* qkv = ws + 4194304;             // 3 x 4194304
    short* ctx = ws + 4 * 4194304;         // 4194304

    cvt_w<<<dim3(1024, 4), 256, 0, stream>>>(Wq, Wk, Wv, Wo, Wb);
    {
      GP p{};
      p.A0 = query; p.A1 = key_; p.A2 = value;
      p.B = Wb; p.b0 = bq; p.b1 = bk; p.b2 = bv;
      p.C = qkv;
      p.lda = 1024; p.ldb = 1024; p.K = 1024;
      p.aBS = 0; p.bBS = 1048576;
      gemm_nt<2, 2, 4, 4, true, M_PROJ><<<dim3(256, 3), 256, 0, stream>>>(p);
    }
    attn_fused<<<dim3(512), 256, 0, stream>>>(
        qkv, qkv + 4194304, qkv + 2 * 4194304, attn, ctx);
    {
      GP p{};
      p.A0 = ctx;
      p.B = Wb + 3 * 1048576;
      p.b0 = bo;
      p.C = out;
      p.lda = 1024; p.ldb = 1024; p.K = 1024;
      p.aBS = 0; p.bBS = 0;
      gemm_nt<2, 2, 4, 4, false, M_OUT><<<dim3(256, 1), 256, 0, stream>>>(p);
    }
  }
}